// Round 1
// baseline (3242.538 us; speedup 1.0000x reference)
//
#include <hip/hip_runtime.h>
#include <hip/hip_bf16.h>
#include <math.h>

#define EMB 128
#define CDIM 12
#define FIN 16
#define NLAYER 5
#define BN_EPS 1e-5f

// signed-float atomic max (works with -inf init)
__device__ __forceinline__ void atomicMaxF(float* a, float v) {
    if (v >= 0.f) atomicMax((int*)a, __float_as_int(v));
    else          atomicMin((unsigned int*)a, __float_as_uint(v));
}

// graph start offsets: batch is sorted, every graph nonempty -> boundaries are +1 steps
__global__ __launch_bounds__(256) void k_gstart(const int* __restrict__ batch,
                                                int* __restrict__ gs, int N, int G) {
    int i = blockIdx.x * 256 + threadIdx.x;
    if (i >= N) return;
    if (i == 0) gs[0] = 0;
    else { int b = batch[i]; if (b != batch[i - 1]) gs[b] = i; }
    if (i == N - 1) gs[G] = N;
}

// h = relu(bn(x @ W1 + b1)); x [N,16], W1 [16,128]
__global__ __launch_bounds__(256) void k_lin16(const float* __restrict__ x, float* __restrict__ out,
        const float* __restrict__ W, const float* __restrict__ lb,
        const float* __restrict__ s, const float* __restrict__ bb,
        const float* __restrict__ m, const float* __restrict__ v, int N) {
    int idx = blockIdx.x * 256 + threadIdx.x;
    if (idx >= N * EMB) return;
    int n = idx >> 7, f = idx & 127;
    float acc = 0.f;
    #pragma unroll
    for (int k = 0; k < FIN; k++) acc += x[n * FIN + k] * W[k * EMB + f];
    acc += lb[f];
    float y = (acc - m[f]) * rsqrtf(v[f] + BN_EPS) * s[f] + bb[f];
    out[idx] = fmaxf(y, 0.f);
}

// out[N,128] = relu(bn(in @ W + lb)); W [128,128] row-major (k-major)
// W staged in LDS (64KB exactly). Thread = 8 nodes x 4 consecutive feats (float4).
__global__ __launch_bounds__(256) void k_lin128(const float* __restrict__ in, float* __restrict__ out,
        const float* __restrict__ W, const float* __restrict__ lb,
        const float* __restrict__ s, const float* __restrict__ bb,
        const float* __restrict__ m, const float* __restrict__ v, int N) {
    __shared__ float Ws[EMB * EMB];
    for (int i = threadIdx.x; i < EMB * EMB; i += 256) Ws[i] = W[i];
    __syncthreads();

    const int fgrp = threadIdx.x & 31;  // feature group -> feats f0..f0+3
    const int ngrp = threadIdx.x >> 5;  // 0..7 -> 8 nodes each
    const int f0 = fgrp * 4;

    // fold BN: y = z*A + B where A = s*rsqrt(v+eps), B = (lb - m)*A + bb
    float4 A, B4;
    {
        float4 sv = *(const float4*)&s[f0];
        float4 bv = *(const float4*)&bb[f0];
        float4 mv = *(const float4*)&m[f0];
        float4 vv = *(const float4*)&v[f0];
        float4 lv = *(const float4*)&lb[f0];
        A.x = sv.x * rsqrtf(vv.x + BN_EPS);
        A.y = sv.y * rsqrtf(vv.y + BN_EPS);
        A.z = sv.z * rsqrtf(vv.z + BN_EPS);
        A.w = sv.w * rsqrtf(vv.w + BN_EPS);
        B4.x = bv.x + (lv.x - mv.x) * A.x;
        B4.y = bv.y + (lv.y - mv.y) * A.y;
        B4.z = bv.z + (lv.z - mv.z) * A.z;
        B4.w = bv.w + (lv.w - mv.w) * A.w;
    }

    int ntiles = (N + 63) >> 6;  // 64 nodes per block-tile
    for (int tile = blockIdx.x; tile < ntiles; tile += gridDim.x) {
        int nb = tile * 64 + ngrp * 8;
        float4 acc[8];
        #pragma unroll
        for (int i = 0; i < 8; i++) acc[i] = make_float4(0.f, 0.f, 0.f, 0.f);

        for (int k = 0; k < EMB; k += 4) {
            float4 wv[4];
            #pragma unroll
            for (int j = 0; j < 4; j++) wv[j] = *(const float4*)&Ws[(k + j) * EMB + f0];
            #pragma unroll
            for (int i = 0; i < 8; i++) {
                int n = min(nb + i, N - 1);
                float4 xv = *(const float4*)&in[n * EMB + k];
                acc[i].x += xv.x * wv[0].x + xv.y * wv[1].x + xv.z * wv[2].x + xv.w * wv[3].x;
                acc[i].y += xv.x * wv[0].y + xv.y * wv[1].y + xv.z * wv[2].y + xv.w * wv[3].y;
                acc[i].z += xv.x * wv[0].z + xv.y * wv[1].z + xv.z * wv[2].z + xv.w * wv[3].z;
                acc[i].w += xv.x * wv[0].w + xv.y * wv[1].w + xv.z * wv[2].w + xv.w * wv[3].w;
            }
        }
        #pragma unroll
        for (int i = 0; i < 8; i++) {
            int n = nb + i;
            if (n < N) {
                float4 o;
                o.x = fmaxf(acc[i].x * A.x + B4.x, 0.f);
                o.y = fmaxf(acc[i].y * A.y + B4.y, 0.f);
                o.z = fmaxf(acc[i].z * A.z + B4.z, 0.f);
                o.w = fmaxf(acc[i].w * A.w + B4.w, 0.f);
                *(float4*)&out[n * EMB + f0] = o;
            }
        }
    }
}

// oth = (1 + eps[l]) * cur   (float4 elementwise)
__global__ __launch_bounds__(256) void k_scale(const float* __restrict__ in, float* __restrict__ out,
                                               const float* __restrict__ epsp, int total4) {
    int idx = blockIdx.x * 256 + threadIdx.x;
    if (idx >= total4) return;
    float se = 1.f + epsp[0];
    float4 v = ((const float4*)in)[idx];
    v.x *= se; v.y *= se; v.z *= se; v.w *= se;
    ((float4*)out)[idx] = v;
}

// agg[dst[e]] += h[src[e]]  (per-(edge,feature) hardware fp32 atomics)
__global__ __launch_bounds__(256) void k_scatter(const float* __restrict__ h, float* __restrict__ agg,
        const int* __restrict__ src, const int* __restrict__ dst, int total) {
    int idx = blockIdx.x * 256 + threadIdx.x;
    if (idx >= total) return;
    int e = idx >> 7, f = idx & 127;
    int sn = src[e], dn = dst[e];
    unsafeAtomicAdd(&agg[dn * EMB + f], h[sn * EMB + f]);
}

__global__ __launch_bounds__(256) void k_fill(float* __restrict__ p, float val, int n) {
    int i = blockIdx.x * 256 + threadIdx.x;
    if (i < n) p[i] = val;
}

// initial readout: out[g] = max over nodes of (h[n] @ init_lin_w + init_lin_b)
// one wave per node; shuffle-reduce 128-dot per target
__global__ __launch_bounds__(256) void k_init_readout(const float* __restrict__ h,
        const int* __restrict__ batch, const float* __restrict__ W,
        const float* __restrict__ lb, float* __restrict__ out, int N) {
    int node = blockIdx.x * 4 + (threadIdx.x >> 6);
    int lane = threadIdx.x & 63;
    if (node >= N) return;
    float h0 = h[node * EMB + lane];
    float h1 = h[node * EMB + 64 + lane];
    int g = batch[node];
    #pragma unroll
    for (int c = 0; c < CDIM; c++) {
        float p = h0 * W[lane * CDIM + c] + h1 * W[(lane + 64) * CDIM + c];
        #pragma unroll
        for (int off = 32; off > 0; off >>= 1) p += __shfl_down(p, off);
        if (lane == 0) atomicMaxF(&out[g * CDIM + c], p + lb[c]);
    }
}

// per-layer readout: out[g] += segment_max(h)[g] @ llin_w[l] + llin_b[l]
// one block (128 thr) per graph; contiguous node range, no atomics
__global__ __launch_bounds__(128) void k_readout(const float* __restrict__ h,
        const int* __restrict__ gs, const float* __restrict__ W,
        const float* __restrict__ lb, float* __restrict__ out, int G) {
    int g = blockIdx.x;
    int t = threadIdx.x;
    int s0 = gs[g], e0 = gs[g + 1];
    float mval = -INFINITY;
    for (int n = s0; n < e0; n++) mval = fmaxf(mval, h[n * EMB + t]);
    __shared__ float mv[EMB];
    mv[t] = mval;
    __syncthreads();
    if (t < CDIM) {
        float acc = 0.f;
        for (int k = 0; k < EMB; k++) acc += mv[k] * W[k * CDIM + t];
        out[g * CDIM + t] += acc + lb[t];
    }
}

extern "C" void kernel_launch(void* const* d_in, const int* in_sizes, int n_in,
                              void* d_out, int out_size, void* d_ws, size_t ws_size,
                              hipStream_t stream) {
    const float* x        = (const float*)d_in[0];
    const int*   ei       = (const int*)d_in[1];
    const int*   batch    = (const int*)d_in[2];
    const float* init_w1  = (const float*)d_in[3];
    const float* init_b1  = (const float*)d_in[4];
    const float* ibn1_s   = (const float*)d_in[5];
    const float* ibn1_b   = (const float*)d_in[6];
    const float* ibn1_m   = (const float*)d_in[7];
    const float* ibn1_v   = (const float*)d_in[8];
    const float* init_w2  = (const float*)d_in[9];
    const float* init_b2  = (const float*)d_in[10];
    const float* ibn2_s   = (const float*)d_in[11];
    const float* ibn2_b   = (const float*)d_in[12];
    const float* ibn2_m   = (const float*)d_in[13];
    const float* ibn2_v   = (const float*)d_in[14];
    const float* ilin_w   = (const float*)d_in[15];
    const float* ilin_b   = (const float*)d_in[16];
    const float* eps      = (const float*)d_in[17];
    const float* lw1      = (const float*)d_in[18];
    const float* lb1      = (const float*)d_in[19];
    const float* lbn1_s   = (const float*)d_in[20];
    const float* lbn1_b   = (const float*)d_in[21];
    const float* lbn1_m   = (const float*)d_in[22];
    const float* lbn1_v   = (const float*)d_in[23];
    const float* lw2      = (const float*)d_in[24];
    const float* lb2      = (const float*)d_in[25];
    const float* lbn2_s   = (const float*)d_in[26];
    const float* lbn2_b   = (const float*)d_in[27];
    const float* lbn2_m   = (const float*)d_in[28];
    const float* lbn2_v   = (const float*)d_in[29];
    const float* llin_w   = (const float*)d_in[30];
    const float* llin_b   = (const float*)d_in[31];

    const int N = in_sizes[0] / FIN;
    const int E = in_sizes[1] / 2;
    const int G = out_size / CDIM;
    const int* src = ei;
    const int* dst = ei + E;
    float* out = (float*)d_out;

    float* bufA = (float*)d_ws;
    float* bufB = bufA + (size_t)N * EMB;
    int*   gs   = (int*)(bufB + (size_t)N * EMB);

    k_gstart<<<(N + 255) / 256, 256, 0, stream>>>(batch, gs, N, G);

    // init MLP
    k_lin16<<<(N * EMB + 255) / 256, 256, 0, stream>>>(x, bufA, init_w1, init_b1,
                                                       ibn1_s, ibn1_b, ibn1_m, ibn1_v, N);
    k_lin128<<<512, 256, 0, stream>>>(bufA, bufB, init_w2, init_b2,
                                      ibn2_s, ibn2_b, ibn2_m, ibn2_v, N);

    // initial readout (linear then segment-max)
    k_fill<<<(G * CDIM + 255) / 256, 256, 0, stream>>>(out, -INFINITY, G * CDIM);
    k_init_readout<<<(N + 3) / 4, 256, 0, stream>>>(bufB, batch, ilin_w, ilin_b, out, N);

    float* cur = bufB;  // holds h
    float* oth = bufA;
    for (int l = 0; l < NLAYER; l++) {
        k_scale<<<(N * EMB / 4 + 255) / 256, 256, 0, stream>>>(cur, oth, eps + l, N * EMB / 4);
        k_scatter<<<(E * EMB + 255) / 256, 256, 0, stream>>>(cur, oth, src, dst, E * EMB);
        k_lin128<<<512, 256, 0, stream>>>(oth, cur, lw1 + l * EMB * EMB, lb1 + l * EMB,
                                          lbn1_s + l * EMB, lbn1_b + l * EMB,
                                          lbn1_m + l * EMB, lbn1_v + l * EMB, N);
        k_lin128<<<512, 256, 0, stream>>>(cur, oth, lw2 + l * EMB * EMB, lb2 + l * EMB,
                                          lbn2_s + l * EMB, lbn2_b + l * EMB,
                                          lbn2_m + l * EMB, lbn2_v + l * EMB, N);
        k_readout<<<G, 128, 0, stream>>>(oth, gs, llin_w + l * EMB * CDIM, llin_b + l * CDIM, out, G);
        float* t = cur; cur = oth; oth = t;
    }
}